// Round 3
// baseline (7360.781 us; speedup 1.0000x reference)
//
#include <hip/hip_runtime.h>
#include <hip/hip_fp16.h>

#define NNODE 10000
#define NEDGE 160000
#define W32 32
#define TE 64          // edges per mlp block
#define HSTR 264       // fp16 row stride for h1/h2 LDS (256 + 8 pad)
#define EASTR 40       // fp16 row stride for ea LDS (32 + 8 pad)

typedef _Float16 f16;
typedef _Float16 f16x8 __attribute__((ext_vector_type(8)));
typedef float f32x4 __attribute__((ext_vector_type(4)));

// ================= weight pack kernels (fp32 -> fp16, MFMA staging order) ===========
// k1p[j*32+c'] = c'<6 ? k1w[c'][j] : 0                  (8192 elems)
__global__ __launch_bounds__(256) void pack_k1(const float* __restrict__ k1w, f16* __restrict__ k1p) {
    int i = blockIdx.x * 256 + threadIdx.x;
    int j = i >> 5, c = i & 31;
    k1p[i] = (c < 6) ? (f16)k1w[c * 256 + j] : (f16)0.f;
}
// k2p[(kk*256+j)*32+c'] = k2w[kk*32+c'][j]              (65536 elems, coalesced read)
__global__ __launch_bounds__(256) void pack_k2(const float* __restrict__ k2w, f16* __restrict__ k2p) {
    int i = blockIdx.x * 256 + threadIdx.x;
    int c = i >> 8, j = i & 255;
    int kk = c >> 5, cp = c & 31;
    k2p[((kk * 256 + j) * 32) + cp] = (f16)k2w[i];
}
// k3p[((nc*8+kk)*256+j)*32+c'] = k3w[kk*32+c'][nc*256+j] (262144 elems, coalesced read)
__global__ __launch_bounds__(256) void pack_k3(const float* __restrict__ k3w, f16* __restrict__ k3p) {
    int i = blockIdx.x * 256 + threadIdx.x;
    int c = i >> 10, col = i & 1023;
    int kk = c >> 5, cp = c & 31, nc = col >> 8, j = col & 255;
    k3p[(((nc * 8 + kk) * 256 + j) * 32) + cp] = (f16)k3w[i];
}

// ================= edge MLP via MFMA: 64 edges/block -> W_T[e][o][i] fp16 ===========
__global__ __launch_bounds__(256) void mlp_kernel(
    const float* __restrict__ ea,
    const f16* __restrict__ k1p, const float* __restrict__ k1b,
    const f16* __restrict__ k2p, const float* __restrict__ k2b,
    const f16* __restrict__ k3p, const float* __restrict__ k3b,
    f16* __restrict__ Wt, int e_start)
{
    __shared__ __align__(16) f16 ea_s[TE * EASTR];
    __shared__ __align__(16) f16 hbuf[TE * HSTR];   // h1, then h2 (A reads go to regs first)
    __shared__ __align__(16) f16 bls[256 * 32];     // one K-step B panel (16 KB)

    const int t = threadIdx.x;
    const int w = t >> 6, lane = t & 63, quad = lane >> 4, l15 = lane & 15;
    const int eloc0 = blockIdx.x * TE;   // chunk-local edge base (W_T index)
    const int e0 = e_start + eloc0;      // global edge base (input index)

    // ---- ea tile as zero-padded fp16 A matrix [64][32] ----
    for (int i = t; i < TE * 32; i += 256) {
        int e = i >> 5, c = i & 31;
        float v = (c < 6) ? ea[(size_t)(e0 + e) * 6 + c] : 0.f;
        ea_s[e * EASTR + c] = (f16)v;
    }
    __syncthreads();

    // ================= Layer 1: (64x32) @ (32x256) -> h1 = relu =================
    {
        f16x8 a = *(const f16x8*)&ea_s[(w * 16 + l15) * EASTR + quad * 8];
        {   // stage k1p (16 KB flat copy)
            const uint4* src = (const uint4*)k1p;
            uint4* dst = (uint4*)bls;
            #pragma unroll
            for (int s = 0; s < 4; ++s) { int id = (w * 4 + s) * 64 + lane; dst[id] = src[id]; }
        }
        __syncthreads();
        f32x4 acc[16];
        #pragma unroll
        for (int nt = 0; nt < 16; ++nt) {
            float b = k1b[nt * 16 + l15];
            acc[nt] = (f32x4){b, b, b, b};
        }
        #pragma unroll
        for (int nt = 0; nt < 16; ++nt) {
            f16x8 bf = *(const f16x8*)&bls[(nt * 16 + l15) * 32 + quad * 8];
            acc[nt] = __builtin_amdgcn_mfma_f32_16x16x32_f16(a, bf, acc[nt], 0, 0, 0);
        }
        __syncthreads();   // bls reads complete before next layer stages
        #pragma unroll
        for (int nt = 0; nt < 16; ++nt)
            #pragma unroll
            for (int r = 0; r < 4; ++r) {
                int e = w * 16 + quad * 4 + r;
                hbuf[e * HSTR + nt * 16 + l15] = (f16)fmaxf(acc[nt][r], 0.f);
            }
    }
    __syncthreads();       // h1 visible

    // ================= Layer 2: (64x256) @ (256x256) -> h2 = relu (in place) =====
    {
        f16x8 a[8];
        #pragma unroll
        for (int kk = 0; kk < 8; ++kk)
            a[kk] = *(const f16x8*)&hbuf[(w * 16 + l15) * HSTR + kk * 32 + quad * 8];
        f32x4 acc[16];
        #pragma unroll
        for (int nt = 0; nt < 16; ++nt) {
            float b = k2b[nt * 16 + l15];
            acc[nt] = (f32x4){b, b, b, b};
        }
        for (int kk = 0; kk < 8; ++kk) {
            __syncthreads();   // prior bls readers done
            const uint4* src = (const uint4*)(k2p + (size_t)kk * 256 * 32);
            uint4* dst = (uint4*)bls;
            #pragma unroll
            for (int s = 0; s < 4; ++s) { int id = (w * 4 + s) * 64 + lane; dst[id] = src[id]; }
            __syncthreads();   // panel staged
            #pragma unroll
            for (int nt = 0; nt < 16; ++nt) {
                f16x8 bf = *(const f16x8*)&bls[(nt * 16 + l15) * 32 + quad * 8];
                acc[nt] = __builtin_amdgcn_mfma_f32_16x16x32_f16(a[kk], bf, acc[nt], 0, 0, 0);
            }
        }
        __syncthreads();   // all waves past A-frag reads & bls reads
        #pragma unroll
        for (int nt = 0; nt < 16; ++nt)
            #pragma unroll
            for (int r = 0; r < 4; ++r) {
                int e = w * 16 + quad * 4 + r;
                hbuf[e * HSTR + nt * 16 + l15] = (f16)fmaxf(acc[nt][r], 0.f);
            }
    }
    __syncthreads();       // h2 visible

    // ================= Layer 3: (64x256) @ (256x1024) -> W_T global ==============
    {
        f16x8 a[8];
        #pragma unroll
        for (int kk = 0; kk < 8; ++kk)
            a[kk] = *(const f16x8*)&hbuf[(w * 16 + l15) * HSTR + kk * 32 + quad * 8];
        for (int nc = 0; nc < 4; ++nc) {
            f32x4 acc[16];
            #pragma unroll
            for (int nt = 0; nt < 16; ++nt) {
                float b = k3b[nc * 256 + nt * 16 + l15];
                acc[nt] = (f32x4){b, b, b, b};
            }
            for (int kk = 0; kk < 8; ++kk) {
                __syncthreads();
                const uint4* src = (const uint4*)(k3p + ((size_t)(nc * 8 + kk)) * 256 * 32);
                uint4* dst = (uint4*)bls;
                #pragma unroll
                for (int s = 0; s < 4; ++s) { int id = (w * 4 + s) * 64 + lane; dst[id] = src[id]; }
                __syncthreads();
                #pragma unroll
                for (int nt = 0; nt < 16; ++nt) {
                    f16x8 bf = *(const f16x8*)&bls[(nt * 16 + l15) * 32 + quad * 8];
                    acc[nt] = __builtin_amdgcn_mfma_f32_16x16x32_f16(a[kk], bf, acc[nt], 0, 0, 0);
                }
            }
            // scatter-store transposed: col c = nc*256+nt*16+l15 -> i=c>>5, o=c&31
            #pragma unroll
            for (int nt = 0; nt < 16; ++nt) {
                int o = ((nt & 1) << 4) + l15;
                int i = nc * 8 + (nt >> 1);
                #pragma unroll
                for (int r = 0; r < 4; ++r) {
                    int e = eloc0 + w * 16 + quad * 4 + r;
                    Wt[(size_t)e * 1024 + o * 32 + i] = (f16)acc[nt][r];
                }
            }
        }
    }
}

// ================= h0 = x @ fc1_w + fc1_b =================
__global__ __launch_bounds__(256) void h0_kernel(
    const float* __restrict__ x, const float* __restrict__ fc1w,
    const float* __restrict__ fc1b, float* __restrict__ h)
{
    int idx = blockIdx.x * 256 + threadIdx.x;   // N*32 exact
    int n = idx >> 5, j = idx & 31;
    h[idx] = x[n] * fc1w[j] + fc1b[j];
}

// ================= degree =================
__global__ __launch_bounds__(256) void deg_kernel(
    const int* __restrict__ ei, float* __restrict__ deg)
{
    int e = blockIdx.x * 256 + threadIdx.x;
    if (e < NEDGE) atomicAdd(&deg[ei[NEDGE + e]], 1.f);
}

// ================= msg: one wave per edge, W_T[e][o][i] vector reads =================
__global__ __launch_bounds__(256) void msg_kernel(
    const int* __restrict__ ei, const f16* __restrict__ Wt,
    const float* __restrict__ h, float* __restrict__ agg, int e_start)
{
    const int t = threadIdx.x;
    const int w = t >> 6, lane = t & 63;
    const int eloc = blockIdx.x * 4 + w;
    const int e = e_start + eloc;
    const int o = lane & 31;
    const int hi16 = (lane & 32) >> 1;            // 0 | 16 : this lane's i-range base
    const int base = (lane & 32) + hi16;          // shfl source base (0 | 48)
    const int src = ei[e], dst = ei[NEDGE + e];
    float hv = h[src * W32 + o];
    const f16x8* wp = (const f16x8*)(Wt + (size_t)eloc * 1024 + o * 32 + hi16);
    f16x8 q0 = wp[0], q1 = wp[1];
    float acc = 0.f;
    #pragma unroll
    for (int k = 0; k < 8; ++k) acc += __shfl(hv, base + k) * (float)q0[k];
    #pragma unroll
    for (int k = 0; k < 8; ++k) acc += __shfl(hv, base + 8 + k) * (float)q1[k];
    acc += __shfl(acc, lane ^ 32);                // combine the two i-halves
    if (lane < 32) atomicAdd(&agg[dst * W32 + o], acc);
}

// ================= node update =================
__global__ __launch_bounds__(256) void update_kernel(
    const float* __restrict__ h_old, float* __restrict__ h_new,
    float* __restrict__ agg, const float* __restrict__ deg,
    const float* __restrict__ rootw, const float* __restrict__ convb)
{
    __shared__ float rw[W32][W32 + 1];
    const int t = threadIdx.x;
    for (int q = t; q < W32 * W32; q += 256)
        rw[q >> 5][q & 31] = rootw[q];
    __syncthreads();
    const int nl = t >> 5, j = t & 31;
    const int n = blockIdx.x * 8 + nl;
    float hv = h_old[n * W32 + j];
    float acc = convb[j];
    #pragma unroll
    for (int k = 0; k < W32; ++k)
        acc += __shfl(hv, k, 32) * rw[k][j];
    float inv = 1.f / fmaxf(deg[n], 1.f);
    int idx = n * W32 + j;
    float a = agg[idx];
    agg[idx] = 0.f;               // re-zero for next depth
    h_new[idx] = fmaxf(a * inv + acc, 0.f);
}

// ================= out = h @ fc2_w + fc2_b =================
__global__ __launch_bounds__(256) void out_kernel(
    const float* __restrict__ h, const float* __restrict__ fc2w,
    const float* __restrict__ fc2b, float* __restrict__ out)
{
    int n = blockIdx.x * 256 + threadIdx.x;
    if (n < NNODE) {
        float a = fc2b[0];
        #pragma unroll
        for (int j = 0; j < W32; ++j)
            a += h[n * W32 + j] * fc2w[j];
        out[n] = a;
    }
}

extern "C" void kernel_launch(void* const* d_in, const int* in_sizes, int n_in,
                              void* d_out, int out_size, void* d_ws, size_t ws_size,
                              hipStream_t stream) {
    const float* x    = (const float*)d_in[0];
    const int*   ei   = (const int*)  d_in[1];
    const float* ea   = (const float*)d_in[2];
    const float* fc1w = (const float*)d_in[3];
    const float* fc1b = (const float*)d_in[4];
    const float* k1w  = (const float*)d_in[5];
    const float* k1b  = (const float*)d_in[6];
    const float* k2w  = (const float*)d_in[7];
    const float* k2b  = (const float*)d_in[8];
    const float* k3w  = (const float*)d_in[9];
    const float* k3b  = (const float*)d_in[10];
    const float* rootw= (const float*)d_in[11];
    const float* convb= (const float*)d_in[12];
    const float* fc2w = (const float*)d_in[13];
    const float* fc2b = (const float*)d_in[14];
    float* out = (float*)d_out;

    // ---- workspace: fixed small buffers + packed weights first, W_T chunk after ----
    const size_t hbytes = (size_t)NNODE * W32 * 4;            // 1,280,000
    char* ws = (char*)d_ws;
    size_t off = 0;
    float* hA  = (float*)(ws + off); off += hbytes;
    float* hB  = (float*)(ws + off); off += hbytes;
    float* agg = (float*)(ws + off); off += hbytes;
    float* deg = (float*)(ws + off); off += 40960;            // NNODE*4 padded
    f16*  k1p  = (f16*)(ws + off);   off += 16384;
    f16*  k2p  = (f16*)(ws + off);   off += 131072;
    f16*  k3p  = (f16*)(ws + off);   off += 524288;
    f16*  Wt   = (f16*)(ws + off);
    const size_t fixed = off;

    long long availC = 0;
    if (ws_size > fixed) availC = (long long)((ws_size - fixed) / 2048);  // 1024 fp16/edge
    int C = (availC > NEDGE) ? NEDGE : (int)availC;
    C &= ~63;                      // multiple of TE
    if (C < TE) return;            // workspace too small: clean failure, no fault

    hipMemsetAsync(deg, 0, (size_t)NNODE * 4, stream);
    hipMemsetAsync(agg, 0, (size_t)NNODE * W32 * 4, stream);

    pack_k1<<<32, 256, 0, stream>>>(k1w, k1p);
    pack_k2<<<256, 256, 0, stream>>>(k2w, k2p);
    pack_k3<<<1024, 256, 0, stream>>>(k3w, k3p);

    h0_kernel<<<NNODE * W32 / 256, 256, 0, stream>>>(x, fc1w, fc1b, hA);
    deg_kernel<<<(NEDGE + 255) / 256, 256, 0, stream>>>(ei, deg);

    const bool full = (C == NEDGE);
    if (full)
        mlp_kernel<<<NEDGE / TE, 256, 0, stream>>>(ea, k1p, k1b, k2p, k2b, k3p, k3b, Wt, 0);

    float* hcur = hA; float* hnext = hB;
    for (int d = 0; d < 4; ++d) {
        for (int es = 0; es < NEDGE; es += C) {
            int ce = (NEDGE - es < C) ? (NEDGE - es) : C;    // multiple of 64
            if (!full)
                mlp_kernel<<<ce / TE, 256, 0, stream>>>(ea, k1p, k1b, k2p, k2b, k3p, k3b, Wt, es);
            msg_kernel<<<ce / 4, 256, 0, stream>>>(ei, Wt, hcur, agg, es);
        }
        update_kernel<<<NNODE / 8, 256, 0, stream>>>(hcur, hnext, agg, deg, rootw, convb);
        float* tmp = hcur; hcur = hnext; hnext = tmp;
    }
    out_kernel<<<(NNODE + 255) / 256, 256, 0, stream>>>(hcur, fc2w, fc2b, out);
}

// Round 4
// 978.218 us; speedup vs baseline: 7.5247x; 7.5247x over previous
//
#include <hip/hip_runtime.h>
#include <hip/hip_fp16.h>

#define NNODE 10000
#define NEDGE 160000
#define W32 32
#define BSTR 40          // f16 row stride for B panels: 80 B -> (col*5+quad)%8 slots, 2-way max (free)
#define PANEL_F16 10240  // 256*40 f16 = 20480 B per K-panel

typedef _Float16 f16;
typedef _Float16 f16x8 __attribute__((ext_vector_type(8)));
typedef float f32x4 __attribute__((ext_vector_type(4)));

// ---- async stage one 20480-B panel into LDS (wave w does slots [w*320, w*320+320)) ----
__device__ __forceinline__ void stage_panel(f16* lds, const f16* g, int w, int lane) {
    #pragma unroll
    for (int i = 0; i < 5; ++i) {
        int slot = w * 320 + i * 64 + lane;           // 16-B slot index
        __builtin_amdgcn_global_load_lds(
            (const __attribute__((address_space(1))) unsigned int*)(g + (size_t)slot * 8),
            (__attribute__((address_space(3))) unsigned int*)(lds + (size_t)(w * 320 + i * 64) * 8),
            16, 0, 0);
    }
}

// ================= weight packs: fp32 -> fp16, B-panel layout [panel][col*40 + k] ========
__global__ __launch_bounds__(256) void pack_k1(const float* __restrict__ k1w, f16* __restrict__ k1p) {
    int t = blockIdx.x * 256 + threadIdx.x;           // 10240
    int j = t / BSTR, c = t % BSTR;
    k1p[t] = (c < 6) ? (f16)k1w[c * 256 + j] : (f16)0.f;
}
__global__ __launch_bounds__(256) void pack_k2(const float* __restrict__ k2w, f16* __restrict__ k2p) {
    int t = blockIdx.x * 256 + threadIdx.x;           // 8*10240
    int kk = t / PANEL_F16, r = t % PANEL_F16;
    int j = r / BSTR, c = r % BSTR;
    k2p[t] = (c < 32) ? (f16)k2w[(size_t)(kk * 32 + c) * 256 + j] : (f16)0.f;
}
__global__ __launch_bounds__(256) void pack_k3(const float* __restrict__ k3w, f16* __restrict__ k3p) {
    int t = blockIdx.x * 256 + threadIdx.x;           // 32*10240
    int p = t / PANEL_F16, r = t % PANEL_F16;
    int nc = p >> 3, kk = p & 7;
    int j = r / BSTR, c = r % BSTR;
    k3p[t] = (c < 32) ? (f16)k3w[(size_t)(kk * 32 + c) * 1024 + nc * 256 + j] : (f16)0.f;
}

// ================= h2 = relu(relu(ea@k1+b1)@k2+b2) for a chunk of edges, fp16 out =======
__global__ __launch_bounds__(256) void h2_kernel(
    const float* __restrict__ ea,
    const f16* __restrict__ k1p, const float* __restrict__ k1b,
    const f16* __restrict__ k2p, const float* __restrict__ k2b,
    f16* __restrict__ h2c, int e_start)
{
    __shared__ __align__(16) f16 bls[256 * BSTR];     // 20480 B
    __shared__ __align__(16) f16 ea_s[64 * BSTR];     // 5120 B
    __shared__ __align__(16) f16 hbuf[64 * 264];      // 33792 B

    const int t = threadIdx.x, w = t >> 6, lane = t & 63, quad = lane >> 4, l15 = lane & 15;
    const int el0 = blockIdx.x * 64;                  // chunk-local
    const int e0 = e_start + el0;                     // global

    for (int i = t; i < 64 * BSTR; i += 256) {
        int e = i / BSTR, c = i % BSTR;
        ea_s[i] = (f16)((c < 6) ? ea[(size_t)(e0 + e) * 6 + c] : 0.f);
    }
    stage_panel(bls, k1p, w, lane);
    __syncthreads();

    // layer 1
    f16x8 a1 = *(const f16x8*)&ea_s[(w * 16 + l15) * BSTR + quad * 8];
    f32x4 acc[16];
    #pragma unroll
    for (int nt = 0; nt < 16; ++nt) { float b = k1b[nt * 16 + l15]; acc[nt] = (f32x4){b, b, b, b}; }
    #pragma unroll
    for (int nt = 0; nt < 16; ++nt) {
        f16x8 bf = *(const f16x8*)&bls[(nt * 16 + l15) * BSTR + quad * 8];
        acc[nt] = __builtin_amdgcn_mfma_f32_16x16x32_f16(a1, bf, acc[nt], 0, 0, 0);
    }
    __syncthreads();
    #pragma unroll
    for (int nt = 0; nt < 16; ++nt)
        #pragma unroll
        for (int r = 0; r < 4; ++r)
            hbuf[(w * 16 + quad * 4 + r) * 264 + nt * 16 + l15] = (f16)fmaxf(acc[nt][r], 0.f);
    __syncthreads();

    // layer 2
    f16x8 a2[8];
    #pragma unroll
    for (int kk = 0; kk < 8; ++kk)
        a2[kk] = *(const f16x8*)&hbuf[(w * 16 + l15) * 264 + kk * 32 + quad * 8];
    #pragma unroll
    for (int nt = 0; nt < 16; ++nt) { float b = k2b[nt * 16 + l15]; acc[nt] = (f32x4){b, b, b, b}; }
    for (int kk = 0; kk < 8; ++kk) {
        __syncthreads();                               // prior panel's readers done
        stage_panel(bls, k2p + (size_t)kk * PANEL_F16, w, lane);
        __syncthreads();                               // panel ready (vmcnt drained)
        #pragma unroll
        for (int nt = 0; nt < 16; ++nt) {
            f16x8 bf = *(const f16x8*)&bls[(nt * 16 + l15) * BSTR + quad * 8];
            acc[nt] = __builtin_amdgcn_mfma_f32_16x16x32_f16(a2[kk], bf, acc[nt], 0, 0, 0);
        }
    }
    #pragma unroll
    for (int nt = 0; nt < 16; ++nt)
        #pragma unroll
        for (int r = 0; r < 4; ++r)
            h2c[(size_t)(el0 + w * 16 + quad * 4 + r) * 256 + nt * 16 + l15] = (f16)fmaxf(acc[nt][r], 0.f);
}

// ========== fused: rebuild W in regs from h2@k3, contract with h[src], scatter to agg ====
// 128 edges/block, wave w owns rows [w*32, w*32+32) as two 16-row M-tiles.
__global__ __launch_bounds__(256) void msg_fused(
    const int* __restrict__ ei, const f16* __restrict__ h2c,
    const f16* __restrict__ k3p, const float* __restrict__ k3b,
    const float* __restrict__ h, float* __restrict__ agg, int e_start)
{
    __shared__ __align__(16) f16 bls[2][256 * BSTR];  // 40960 B double buffer
    __shared__ f16 h_s[128 * 33];                     // 8448 B, padded stride 33
    __shared__ int dst_s[128];

    const int t = threadIdx.x, w = t >> 6, lane = t & 63, quad = lane >> 4, l15 = lane & 15;
    const int el0 = blockIdx.x * 128;                 // chunk-local
    const int e0 = e_start + el0;                     // global

    if (t < 128) dst_s[t] = ei[NEDGE + e0 + t];
    {   // gather h[src] as fp16: thread handles half a row
        int e = t >> 1, i0 = (t & 1) * 16;
        int srcn = ei[e0 + e];
        const float* hr = h + (size_t)srcn * 32 + i0;
        #pragma unroll
        for (int j = 0; j < 16; ++j) h_s[e * 33 + i0 + j] = (f16)hr[j];
    }
    stage_panel(bls[0], k3p, w, lane);                // panel 0 async

    float msg[2][4][2];
    #pragma unroll
    for (int m = 0; m < 2; ++m)
        #pragma unroll
        for (int r = 0; r < 4; ++r) { msg[m][r][0] = 0.f; msg[m][r][1] = 0.f; }

    f32x4 acc[2][16];
    __syncthreads();                                  // h_s/dst_s + panel 0 ready

    for (int p = 0; p < 32; ++p) {
        const int nc = p >> 3, kk = p & 7;
        if (p) __syncthreads();                       // panel p ready; p+1 buffer free
        if (p < 31) stage_panel(bls[(p + 1) & 1], k3p + (size_t)(p + 1) * PANEL_F16, w, lane);

        // A fragments straight from global h2 (row read fully by one lane -> full 64B lines)
        const size_t arow0 = (size_t)(el0 + w * 32 + l15) * 256 + kk * 32 + quad * 8;
        f16x8 a0 = *(const f16x8*)(h2c + arow0);
        f16x8 a1 = *(const f16x8*)(h2c + arow0 + 16 * 256);

        if (kk == 0) {
            #pragma unroll
            for (int nt = 0; nt < 16; ++nt) {
                float b = k3b[nc * 256 + nt * 16 + l15];
                acc[0][nt] = (f32x4){b, b, b, b};
                acc[1][nt] = (f32x4){b, b, b, b};
            }
        }
        const f16* B = bls[p & 1];
        #pragma unroll
        for (int nt = 0; nt < 16; ++nt) {
            f16x8 bf = *(const f16x8*)&B[(nt * 16 + l15) * BSTR + quad * 8];
            acc[0][nt] = __builtin_amdgcn_mfma_f32_16x16x32_f16(a0, bf, acc[0][nt], 0, 0, 0);
            acc[1][nt] = __builtin_amdgcn_mfma_f32_16x16x32_f16(a1, bf, acc[1][nt], 0, 0, 0);
        }
        if (kk == 7) {   // fold this nc's W columns into msg: i = nc*8 + (nt>>1), o = (nt&1)*16+l15
            #pragma unroll
            for (int m = 0; m < 2; ++m)
                #pragma unroll
                for (int h8 = 0; h8 < 8; ++h8)
                    #pragma unroll
                    for (int r = 0; r < 4; ++r) {
                        float hv = (float)h_s[(w * 32 + m * 16 + quad * 4 + r) * 33 + nc * 8 + h8];
                        msg[m][r][0] += hv * acc[m][2 * h8][r];
                        msg[m][r][1] += hv * acc[m][2 * h8 + 1][r];
                    }
        }
    }
    #pragma unroll
    for (int m = 0; m < 2; ++m)
        #pragma unroll
        for (int r = 0; r < 4; ++r) {
            int d = dst_s[w * 32 + m * 16 + quad * 4 + r];
            atomicAdd(&agg[d * W32 + l15],      msg[m][r][0]);
            atomicAdd(&agg[d * W32 + 16 + l15], msg[m][r][1]);
        }
}

// ================= small kernels (unchanged from round 3, all passed) =================
__global__ __launch_bounds__(256) void h0_kernel(
    const float* __restrict__ x, const float* __restrict__ fc1w,
    const float* __restrict__ fc1b, float* __restrict__ h)
{
    int idx = blockIdx.x * 256 + threadIdx.x;
    int n = idx >> 5, j = idx & 31;
    h[idx] = x[n] * fc1w[j] + fc1b[j];
}

__global__ __launch_bounds__(256) void deg_kernel(
    const int* __restrict__ ei, float* __restrict__ deg)
{
    int e = blockIdx.x * 256 + threadIdx.x;
    if (e < NEDGE) atomicAdd(&deg[ei[NEDGE + e]], 1.f);
}

__global__ __launch_bounds__(256) void update_kernel(
    const float* __restrict__ h_old, float* __restrict__ h_new,
    float* __restrict__ agg, const float* __restrict__ deg,
    const float* __restrict__ rootw, const float* __restrict__ convb)
{
    __shared__ float rw[W32][W32 + 1];
    const int t = threadIdx.x;
    for (int q = t; q < W32 * W32; q += 256)
        rw[q >> 5][q & 31] = rootw[q];
    __syncthreads();
    const int nl = t >> 5, j = t & 31;
    const int n = blockIdx.x * 8 + nl;
    float hv = h_old[n * W32 + j];
    float acc = convb[j];
    #pragma unroll
    for (int k = 0; k < W32; ++k)
        acc += __shfl(hv, k, 32) * rw[k][j];
    float inv = 1.f / fmaxf(deg[n], 1.f);
    int idx = n * W32 + j;
    float a = agg[idx];
    agg[idx] = 0.f;
    h_new[idx] = fmaxf(a * inv + acc, 0.f);
}

__global__ __launch_bounds__(256) void out_kernel(
    const float* __restrict__ h, const float* __restrict__ fc2w,
    const float* __restrict__ fc2b, float* __restrict__ out)
{
    int n = blockIdx.x * 256 + threadIdx.x;
    if (n < NNODE) {
        float a = fc2b[0];
        #pragma unroll
        for (int j = 0; j < W32; ++j)
            a += h[n * W32 + j] * fc2w[j];
        out[n] = a;
    }
}

extern "C" void kernel_launch(void* const* d_in, const int* in_sizes, int n_in,
                              void* d_out, int out_size, void* d_ws, size_t ws_size,
                              hipStream_t stream) {
    const float* x    = (const float*)d_in[0];
    const int*   ei   = (const int*)  d_in[1];
    const float* ea   = (const float*)d_in[2];
    const float* fc1w = (const float*)d_in[3];
    const float* fc1b = (const float*)d_in[4];
    const float* k1w  = (const float*)d_in[5];
    const float* k1b  = (const float*)d_in[6];
    const float* k2w  = (const float*)d_in[7];
    const float* k2b  = (const float*)d_in[8];
    const float* k3w  = (const float*)d_in[9];
    const float* k3b  = (const float*)d_in[10];
    const float* rootw= (const float*)d_in[11];
    const float* convb= (const float*)d_in[12];
    const float* fc2w = (const float*)d_in[13];
    const float* fc2b = (const float*)d_in[14];
    float* out = (float*)d_out;

    // workspace: fixed small buffers, then adaptive h2 chunk (512 B/edge)
    const size_t hbytes = (size_t)NNODE * W32 * 4;  // 1,280,000
    char* ws = (char*)d_ws;
    size_t off = 0;
    float* hA  = (float*)(ws + off); off += hbytes;
    float* hB  = (float*)(ws + off); off += hbytes;
    float* agg = (float*)(ws + off); off += hbytes;
    float* deg = (float*)(ws + off); off += 40960;
    f16*  k1p  = (f16*)(ws + off);   off += 20480;
    f16*  k2p  = (f16*)(ws + off);   off += 163840;
    f16*  k3p  = (f16*)(ws + off);   off += 655360;
    f16*  h2b  = (f16*)(ws + off);
    const size_t fixed = off;

    long long availC = 0;
    if (ws_size > fixed) availC = (long long)((ws_size - fixed) / 512);   // 256 f16 per edge
    int C = (availC > NEDGE) ? NEDGE : (int)availC;
    C &= ~127;
    if (C < 128) return;   // workspace too small: clean failure, no fault

    hipMemsetAsync(deg, 0, (size_t)NNODE * 4, stream);
    hipMemsetAsync(agg, 0, (size_t)NNODE * W32 * 4, stream);

    pack_k1<<<40, 256, 0, stream>>>(k1w, k1p);
    pack_k2<<<320, 256, 0, stream>>>(k2w, k2p);
    pack_k3<<<1280, 256, 0, stream>>>(k3w, k3p);

    h0_kernel<<<NNODE * W32 / 256, 256, 0, stream>>>(x, fc1w, fc1b, hA);
    deg_kernel<<<(NEDGE + 255) / 256, 256, 0, stream>>>(ei, deg);

    const bool full = (C == NEDGE);
    if (full)
        h2_kernel<<<NEDGE / 64, 256, 0, stream>>>(ea, k1p, k1b, k2p, k2b, h2b, 0);

    float* hcur = hA; float* hnext = hB;
    for (int d = 0; d < 4; ++d) {
        for (int es = 0; es < NEDGE; es += C) {
            int ce = (NEDGE - es < C) ? (NEDGE - es) : C;   // multiple of 128
            if (!full)
                h2_kernel<<<ce / 64, 256, 0, stream>>>(ea, k1p, k1b, k2p, k2b, h2b, es);
            msg_fused<<<ce / 128, 256, 0, stream>>>(ei, h2b, k3p, k3b, hcur, agg, es);
        }
        update_kernel<<<NNODE / 8, 256, 0, stream>>>(hcur, hnext, agg, deg, rootw, convb);
        float* tmp = hcur; hcur = hnext; hnext = tmp;
    }
    out_kernel<<<(NNODE + 255) / 256, 256, 0, stream>>>(hcur, fc2w, fc2b, out);
}

// Round 5
// 906.648 us; speedup vs baseline: 8.1187x; 1.0789x over previous
//
#include <hip/hip_runtime.h>
#include <hip/hip_fp16.h>

#define NNODE 10000
#define NEDGE 160000
#define W32 32
#define BSTR 40          // f16 row stride for B panels (80 B, 16B-aligned)
#define PANEL_F16 10240  // h2 panels: 256 cols * 40
#define PANEL3_F16 5120  // msg panels: 128 cols * 40

typedef _Float16 f16;
typedef _Float16 f16x4 __attribute__((ext_vector_type(4)));
typedef _Float16 f16x8 __attribute__((ext_vector_type(8)));
typedef float f32x4 __attribute__((ext_vector_type(4)));

// ---- stage one 20480-B panel (1280 slots): wave w does slots [w*320, w*320+320) ----
__device__ __forceinline__ void stage_panel(f16* lds, const f16* g, int w, int lane) {
    #pragma unroll
    for (int i = 0; i < 5; ++i) {
        int slot = w * 320 + i * 64 + lane;
        __builtin_amdgcn_global_load_lds(
            (const __attribute__((address_space(1))) unsigned int*)(g + (size_t)slot * 8),
            (__attribute__((address_space(3))) unsigned int*)(lds + (size_t)(w * 320 + i * 64) * 8),
            16, 0, 0);
    }
}

// ---- stage one 10240-B panel (640 slots): 2 full passes + waves 0-1 half pass ----
__device__ __forceinline__ void stage_panel10k(f16* lds, const f16* g, int w, int lane) {
    #pragma unroll
    for (int i = 0; i < 2; ++i) {
        int base = i * 256 + w * 64;
        __builtin_amdgcn_global_load_lds(
            (const __attribute__((address_space(1))) unsigned int*)(g + (size_t)(base + lane) * 8),
            (__attribute__((address_space(3))) unsigned int*)(lds + (size_t)base * 8),
            16, 0, 0);
    }
    if (w < 2) {   // wave-uniform branch
        int base = 512 + w * 64;
        __builtin_amdgcn_global_load_lds(
            (const __attribute__((address_space(1))) unsigned int*)(g + (size_t)(base + lane) * 8),
            (__attribute__((address_space(3))) unsigned int*)(lds + (size_t)base * 8),
            16, 0, 0);
    }
}

// ================= weight packs =================
__global__ __launch_bounds__(256) void pack_k1(const float* __restrict__ k1w, f16* __restrict__ k1p) {
    int t = blockIdx.x * 256 + threadIdx.x;           // 10240
    int j = t / BSTR, c = t % BSTR;
    k1p[t] = (c < 6) ? (f16)k1w[c * 256 + j] : (f16)0.f;
}
__global__ __launch_bounds__(256) void pack_k2(const float* __restrict__ k2w, f16* __restrict__ k2p) {
    int t = blockIdx.x * 256 + threadIdx.x;           // 8*10240
    int kk = t / PANEL_F16, r = t % PANEL_F16;
    int j = r / BSTR, c = r % BSTR;
    k2p[t] = (c < 32) ? (f16)k2w[(size_t)(kk * 32 + c) * 256 + j] : (f16)0.f;
}
// k3 panels of 128 cols: panel p = np*8+kk holds k3[kk*32+c][np*128+j]
__global__ __launch_bounds__(256) void pack_k3(const float* __restrict__ k3w, f16* __restrict__ k3p) {
    int t = blockIdx.x * 256 + threadIdx.x;           // 64*5120
    int p = t / PANEL3_F16, r = t % PANEL3_F16;
    int np = p >> 3, kk = p & 7;
    int j = r / BSTR, c = r % BSTR;
    k3p[t] = (c < 32) ? (f16)k3w[(size_t)(kk * 32 + c) * 1024 + np * 128 + j] : (f16)0.f;
}

// ================= h2 = relu(relu(ea@k1+b1)@k2+b2), fp16 out (unchanged) =================
__global__ __launch_bounds__(256) void h2_kernel(
    const float* __restrict__ ea,
    const f16* __restrict__ k1p, const float* __restrict__ k1b,
    const f16* __restrict__ k2p, const float* __restrict__ k2b,
    f16* __restrict__ h2c, int e_start)
{
    __shared__ __align__(16) f16 bls[256 * BSTR];
    __shared__ __align__(16) f16 ea_s[64 * BSTR];
    __shared__ __align__(16) f16 hbuf[64 * 264];

    const int t = threadIdx.x, w = t >> 6, lane = t & 63, quad = lane >> 4, l15 = lane & 15;
    const int el0 = blockIdx.x * 64;
    const int e0 = e_start + el0;

    for (int i = t; i < 64 * BSTR; i += 256) {
        int e = i / BSTR, c = i % BSTR;
        ea_s[i] = (f16)((c < 6) ? ea[(size_t)(e0 + e) * 6 + c] : 0.f);
    }
    stage_panel(bls, k1p, w, lane);
    __syncthreads();

    f16x8 a1 = *(const f16x8*)&ea_s[(w * 16 + l15) * BSTR + quad * 8];
    f32x4 acc[16];
    #pragma unroll
    for (int nt = 0; nt < 16; ++nt) { float b = k1b[nt * 16 + l15]; acc[nt] = (f32x4){b, b, b, b}; }
    #pragma unroll
    for (int nt = 0; nt < 16; ++nt) {
        f16x8 bf = *(const f16x8*)&bls[(nt * 16 + l15) * BSTR + quad * 8];
        acc[nt] = __builtin_amdgcn_mfma_f32_16x16x32_f16(a1, bf, acc[nt], 0, 0, 0);
    }
    __syncthreads();
    #pragma unroll
    for (int nt = 0; nt < 16; ++nt)
        #pragma unroll
        for (int r = 0; r < 4; ++r)
            hbuf[(w * 16 + quad * 4 + r) * 264 + nt * 16 + l15] = (f16)fmaxf(acc[nt][r], 0.f);
    __syncthreads();

    f16x8 a2[8];
    #pragma unroll
    for (int kk = 0; kk < 8; ++kk)
        a2[kk] = *(const f16x8*)&hbuf[(w * 16 + l15) * 264 + kk * 32 + quad * 8];
    #pragma unroll
    for (int nt = 0; nt < 16; ++nt) { float b = k2b[nt * 16 + l15]; acc[nt] = (f32x4){b, b, b, b}; }
    for (int kk = 0; kk < 8; ++kk) {
        __syncthreads();
        stage_panel(bls, k2p + (size_t)kk * PANEL_F16, w, lane);
        __syncthreads();
        #pragma unroll
        for (int nt = 0; nt < 16; ++nt) {
            f16x8 bf = *(const f16x8*)&bls[(nt * 16 + l15) * BSTR + quad * 8];
            acc[nt] = __builtin_amdgcn_mfma_f32_16x16x32_f16(a2[kk], bf, acc[nt], 0, 0, 0);
        }
    }
    #pragma unroll
    for (int nt = 0; nt < 16; ++nt)
        #pragma unroll
        for (int r = 0; r < 4; ++r)
            h2c[(size_t)(el0 + w * 16 + quad * 4 + r) * 256 + nt * 16 + l15] = (f16)fmaxf(acc[nt][r], 0.f);
}

// ========== fused: W = h2@k3 in regs, contract with h[src], scatter to agg ==========
// 256 edges/block; wave w owns rows [w*64, w*64+64) = 4 M-tiles of 16.
// N processed in 8 panels of 128 cols; K in 8 steps of 32.
__global__ __launch_bounds__(256, 2) void msg_fused(
    const int* __restrict__ ei, const f16* __restrict__ h2c,
    const f16* __restrict__ k3p, const float* __restrict__ k3b,
    const float* __restrict__ h, float* __restrict__ agg, int e_start)
{
    __shared__ __align__(16) f16 bls[2][PANEL3_F16];  // 20480 B double buffer
    __shared__ __align__(16) f16 h_s[256 * 36];       // 18432 B, stride 36 (8B-aligned f16x4)
    __shared__ int dst_s[256];

    const int t = threadIdx.x, w = t >> 6, lane = t & 63, quad = lane >> 4, l15 = lane & 15;
    const int el0 = blockIdx.x * 256;                 // chunk-local
    const int e0 = e_start + el0;                     // global

    dst_s[t] = ei[NEDGE + e0 + t];
    {   // gather h[src] as fp16: one thread per edge row
        int srcn = ei[e0 + t];
        const float4* hr = (const float4*)(h + (size_t)srcn * 32);
        f16* dp = &h_s[t * 36];
        #pragma unroll
        for (int qq = 0; qq < 8; ++qq) {
            float4 v = hr[qq];
            dp[qq * 4 + 0] = (f16)v.x; dp[qq * 4 + 1] = (f16)v.y;
            dp[qq * 4 + 2] = (f16)v.z; dp[qq * 4 + 3] = (f16)v.w;
        }
    }
    stage_panel10k(bls[0], k3p, w, lane);             // panel 0 async

    float msg[4][4][2];
    #pragma unroll
    for (int m = 0; m < 4; ++m)
        #pragma unroll
        for (int r = 0; r < 4; ++r) { msg[m][r][0] = 0.f; msg[m][r][1] = 0.f; }

    f32x4 acc[4][8];
    __syncthreads();                                  // h_s/dst_s + panel 0 ready

    for (int it = 0; it < 64; ++it) {
        const int np = it >> 3, kk = it & 7;
        if (it) __syncthreads();                      // panel `it` ready; buffer (it+1)&1 free
        if (it < 63) stage_panel10k(bls[(it + 1) & 1], k3p + (size_t)(it + 1) * PANEL3_F16, w, lane);

        // A fragments from global h2 (L2/L3-resident)
        f16x8 a[4];
        #pragma unroll
        for (int m = 0; m < 4; ++m)
            a[m] = *(const f16x8*)(h2c + (size_t)(el0 + w * 64 + m * 16 + l15) * 256 + kk * 32 + quad * 8);

        if (kk == 0) {
            #pragma unroll
            for (int nt = 0; nt < 8; ++nt) {
                float b = k3b[np * 128 + nt * 16 + l15];
                #pragma unroll
                for (int m = 0; m < 4; ++m) acc[m][nt] = (f32x4){b, b, b, b};
            }
        }
        const f16* B = bls[it & 1];
        #pragma unroll
        for (int nt = 0; nt < 8; ++nt) {
            f16x8 bf = *(const f16x8*)&B[(nt * 16 + l15) * BSTR + quad * 8];
            #pragma unroll
            for (int m = 0; m < 4; ++m)
                acc[m][nt] = __builtin_amdgcn_mfma_f32_16x16x32_f16(a[m], bf, acc[m][nt], 0, 0, 0);
        }
        if (kk == 7) {   // fold np's W cols: i = np*4+(nt>>1), o = (nt&1)*16+l15
            #pragma unroll
            for (int m = 0; m < 4; ++m)
                #pragma unroll
                for (int r = 0; r < 4; ++r) {
                    int row = w * 64 + m * 16 + quad * 4 + r;
                    f16x4 h4 = *(const f16x4*)&h_s[row * 36 + np * 4];
                    #pragma unroll
                    for (int nt = 0; nt < 8; ++nt)
                        msg[m][r][nt & 1] += (float)h4[nt >> 1] * acc[m][nt][r];
                }
        }
    }
    #pragma unroll
    for (int m = 0; m < 4; ++m)
        #pragma unroll
        for (int r = 0; r < 4; ++r) {
            int d = dst_s[w * 64 + m * 16 + quad * 4 + r];
            atomicAdd(&agg[d * W32 + l15],      msg[m][r][0]);
            atomicAdd(&agg[d * W32 + 16 + l15], msg[m][r][1]);
        }
}

// ================= small kernels =================
__global__ __launch_bounds__(256) void h0_kernel(
    const float* __restrict__ x, const float* __restrict__ fc1w,
    const float* __restrict__ fc1b, float* __restrict__ h)
{
    int idx = blockIdx.x * 256 + threadIdx.x;
    int n = idx >> 5, j = idx & 31;
    h[idx] = x[n] * fc1w[j] + fc1b[j];
}

__global__ __launch_bounds__(256) void deg_kernel(
    const int* __restrict__ ei, float* __restrict__ deg)
{
    int e = blockIdx.x * 256 + threadIdx.x;
    if (e < NEDGE) atomicAdd(&deg[ei[NEDGE + e]], 1.f);
}

__global__ __launch_bounds__(256) void update_kernel(
    const float* __restrict__ h_old, float* __restrict__ h_new,
    float* __restrict__ agg, const float* __restrict__ deg,
    const float* __restrict__ rootw, const float* __restrict__ convb)
{
    __shared__ float rw[W32][W32 + 1];
    const int t = threadIdx.x;
    for (int q = t; q < W32 * W32; q += 256)
        rw[q >> 5][q & 31] = rootw[q];
    __syncthreads();
    const int nl = t >> 5, j = t & 31;
    const int n = blockIdx.x * 8 + nl;
    float hv = h_old[n * W32 + j];
    float acc = convb[j];
    #pragma unroll
    for (int k = 0; k < W32; ++k)
        acc += __shfl(hv, k, 32) * rw[k][j];
    float inv = 1.f / fmaxf(deg[n], 1.f);
    int idx = n * W32 + j;
    float a = agg[idx];
    agg[idx] = 0.f;
    h_new[idx] = fmaxf(a * inv + acc, 0.f);
}

__global__ __launch_bounds__(256) void out_kernel(
    const float* __restrict__ h, const float* __restrict__ fc2w,
    const float* __restrict__ fc2b, float* __restrict__ out)
{
    int n = blockIdx.x * 256 + threadIdx.x;
    if (n < NNODE) {
        float a = fc2b[0];
        #pragma unroll
        for (int j = 0; j < W32; ++j)
            a += h[n * W32 + j] * fc2w[j];
        out[n] = a;
    }
}

extern "C" void kernel_launch(void* const* d_in, const int* in_sizes, int n_in,
                              void* d_out, int out_size, void* d_ws, size_t ws_size,
                              hipStream_t stream) {
    const float* x    = (const float*)d_in[0];
    const int*   ei   = (const int*)  d_in[1];
    const float* ea   = (const float*)d_in[2];
    const float* fc1w = (const float*)d_in[3];
    const float* fc1b = (const float*)d_in[4];
    const float* k1w  = (const float*)d_in[5];
    const float* k1b  = (const float*)d_in[6];
    const float* k2w  = (const float*)d_in[7];
    const float* k2b  = (const float*)d_in[8];
    const float* k3w  = (const float*)d_in[9];
    const float* k3b  = (const float*)d_in[10];
    const float* rootw= (const float*)d_in[11];
    const float* convb= (const float*)d_in[12];
    const float* fc2w = (const float*)d_in[13];
    const float* fc2b = (const float*)d_in[14];
    float* out = (float*)d_out;

    const size_t hbytes = (size_t)NNODE * W32 * 4;
    char* ws = (char*)d_ws;
    size_t off = 0;
    float* hA  = (float*)(ws + off); off += hbytes;
    float* hB  = (float*)(ws + off); off += hbytes;
    float* agg = (float*)(ws + off); off += hbytes;
    float* deg = (float*)(ws + off); off += 40960;
    f16*  k1p  = (f16*)(ws + off);   off += 20480;
    f16*  k2p  = (f16*)(ws + off);   off += 163840;
    f16*  k3p  = (f16*)(ws + off);   off += 655360;
    f16*  h2b  = (f16*)(ws + off);
    const size_t fixed = off;

    long long availC = 0;
    if (ws_size > fixed) availC = (long long)((ws_size - fixed) / 512);   // 256 f16/edge
    int C = (availC > NEDGE) ? NEDGE : (int)availC;
    C &= ~255;                     // multiple of 256 (msg block) and 64 (h2 block)
    if (C < 256) return;           // workspace too small: clean failure, no fault

    hipMemsetAsync(deg, 0, (size_t)NNODE * 4, stream);
    hipMemsetAsync(agg, 0, (size_t)NNODE * W32 * 4, stream);

    pack_k1<<<40, 256, 0, stream>>>(k1w, k1p);
    pack_k2<<<320, 256, 0, stream>>>(k2w, k2p);
    pack_k3<<<1280, 256, 0, stream>>>(k3w, k3p);

    h0_kernel<<<NNODE * W32 / 256, 256, 0, stream>>>(x, fc1w, fc1b, hA);
    deg_kernel<<<(NEDGE + 255) / 256, 256, 0, stream>>>(ei, deg);

    const bool full = (C == NEDGE);
    if (full)
        h2_kernel<<<NEDGE / 64, 256, 0, stream>>>(ea, k1p, k1b, k2p, k2b, h2b, 0);

    float* hcur = hA; float* hnext = hB;
    for (int d = 0; d < 4; ++d) {
        for (int es = 0; es < NEDGE; es += C) {
            int ce = (NEDGE - es < C) ? (NEDGE - es) : C;   // multiple of 256
            if (!full)
                h2_kernel<<<ce / 64, 256, 0, stream>>>(ea, k1p, k1b, k2p, k2b, h2b, es);
            msg_fused<<<ce / 256, 256, 0, stream>>>(ei, h2b, k3p, k3b, hcur, agg, es);
        }
        update_kernel<<<NNODE / 8, 256, 0, stream>>>(hcur, hnext, agg, deg, rootw, convb);
        float* tmp = hcur; hcur = hnext; hnext = tmp;
    }
    out_kernel<<<(NNODE + 255) / 256, 256, 0, stream>>>(hcur, fc2w, fc2b, out);
}